// Round 8
// baseline (181.864 us; speedup 1.0000x reference)
//
#include <hip/hip_runtime.h>

// Fixed geometry: input (1,16,16,16) -> NIN=4096; kernel (32,16,3,3), pad1 stride1 -> NOUT=8192
#define O_CH  32
#define C_CH  16
#define HH    16
#define WW    16
#define NPIX  256
#define NIN   4096
#define NOUT  8192
#define NB_BOUNDS  32     // blocks 0..31: bounds + concrete forward + bias_vec
#define NB_WEIGHTS 2048   // blocks 32..2079: weight matrix, global linear sweep

typedef float v4f __attribute__((ext_vector_type(4)));

// out layout (floats): x_out[8192] | lb[8192] | ub[8192] | weights[4096*8192] | bias_vec[8192]
//
// weights[n=(c,h,w)][col=(o,ph,pw)] = K[o,c,h-ph+1,w-pw+1] when offsets in [0,3), else 0.
//
// This round: R7 kernel unchanged (passing, absmax 3.9e-3) + an appended
// DIAGNOSTIC dispatch that writes the identical 134 MB weights pattern into
// d_ws (the buffer the harness's own fillBuffer sweeps at 6.4 TB/s).
// The dur_us delta vs R7 (=160) cleanly measures our store machinery's
// bandwidth on a known-fast buffer, distinguishing "d_out is slow" (H1)
// from "our kernel's stores are slow" (H2). Idempotent, same work every
// call, d_ws is re-poisoned by the harness before every timed launch.

__device__ __forceinline__ void weights_sweep(const float* __restrict__ wk,
                                              float* __restrict__ dst,
                                              int bw, int tid) {
    const int nb  = bw >> 3;              // row base: n = c*256 + nb
    const int r   = (bw & 7) * 256 + tid; // float4 column index (0..2047)
    const int o   = r >> 6;
    const int p   = r & 63;
    const int ph  = p >> 2;
    const int pw0 = (p & 3) << 2;
    const int h   = nb >> 4;
    const int w   = nb & 15;
    const int kh  = h - ph + 1;
    const bool kvalid = (unsigned)kh < 3u;
    const int  khc = kvalid ? kh : 0;     // clamped for safe addressing
    const int  kw0 = w - pw0 + 1;         // kw of component m is kw0-m

    // loop-invariant component selectors (compiler hoists the compares)
    const bool vx0 = kvalid && kw0 == 0, vx1 = kvalid && kw0 == 1, vx2 = kvalid && kw0 == 2;
    const bool vy0 = kvalid && kw0 == 1, vy1 = kvalid && kw0 == 2, vy2 = kvalid && kw0 == 3;
    const bool vz0 = kvalid && kw0 == 2, vz1 = kvalid && kw0 == 3, vz2 = kvalid && kw0 == 4;
    const bool vw0 = kvalid && kw0 == 3, vw1 = kvalid && kw0 == 4, vw2 = kvalid && kw0 == 5;

    const float* kb = wk + (o * C_CH * 3 + khc) * 3;  // c = 0 slice
    v4f* p4 = (v4f*)dst + (size_t)bw * 256 + tid;

    #pragma unroll
    for (int c = 0; c < C_CH; ++c) {      // c == sweep iteration
        const float k0 = kb[0], k1 = kb[1], k2 = kb[2];
        v4f v;
        v.x = vx0 ? k0 : (vx1 ? k1 : (vx2 ? k2 : 0.f));
        v.y = vy0 ? k0 : (vy1 ? k1 : (vy2 ? k2 : 0.f));
        v.z = vz0 ? k0 : (vz1 ? k1 : (vz2 ? k2 : 0.f));
        v.w = vw0 ? k0 : (vw1 ? k1 : (vw2 ? k2 : 0.f));
        *p4 = v;                          // plain store, 1 KiB/wave contiguous
        p4 += 524288;                     // +8 MiB: next grid sweep step
        kb += 9;                          // next input channel
    }
}

__global__ __launch_bounds__(256) void fused_deeppoly_kernel(
    const float* __restrict__ x,
    const float* __restrict__ lb,
    const float* __restrict__ ub,
    const float* __restrict__ wk,
    const float* __restrict__ bias,
    float* __restrict__ out) {
    const int b   = blockIdx.x;
    const int tid = threadIdx.x;

    if (b >= NB_BOUNDS) {
        weights_sweep(wk, out + 3 * NOUT, b - NB_BOUNDS, tid);
    } else {
        // ---------------- bounds + concrete forward + bias_vec ----------------
        const int o  = b;
        const int ph = tid >> 4, pw = tid & 15;
        const float* kb_base = wk + o * C_CH * 9;
        float xa = 0.f, la = 0.f, ua = 0.f;
        #pragma unroll
        for (int c = 0; c < C_CH; ++c) {
            #pragma unroll
            for (int kh = 0; kh < 3; ++kh) {
                int h = ph + kh - 1;
                if ((unsigned)h >= (unsigned)HH) continue;
                #pragma unroll
                for (int kw = 0; kw < 3; ++kw) {
                    int w = pw + kw - 1;
                    if ((unsigned)w >= (unsigned)WW) continue;
                    float k   = kb_base[c * 9 + kh * 3 + kw];
                    int   idx = c * NPIX + h * WW + w;
                    xa = fmaf(k, x[idx], xa);
                    float lv = lb[idx], uv = ub[idx];
                    la = fmaf(k, (k < 0.f) ? uv : lv, la);
                    ua = fmaf(k, (k < 0.f) ? lv : uv, ua);
                }
            }
        }
        const int   t  = o * 256 + tid;
        const float bv = bias[o];
        out[t]            = xa + bv;         // x_out   (bias once)
        out[NOUT + t]     = la + 3.f * bv;   // lb_new  (bias 3x, per reference)
        out[2 * NOUT + t] = ua + 3.f * bv;   // ub_new
        out[(size_t)3 * NOUT + (size_t)NIN * NOUT + t] = bv;  // bias_vec
    }
}

// Diagnostic: identical weights sweep, but into d_ws (known-fast buffer).
__global__ __launch_bounds__(256) void weights_probe_kernel(
    const float* __restrict__ wk, float* __restrict__ dst) {
    weights_sweep(wk, dst, blockIdx.x, threadIdx.x);
}

extern "C" void kernel_launch(void* const* d_in, const int* in_sizes, int n_in,
                              void* d_out, int out_size, void* d_ws, size_t ws_size,
                              hipStream_t stream) {
    const float* x    = (const float*)d_in[0];
    const float* lbp  = (const float*)d_in[1];
    const float* ubp  = (const float*)d_in[2];
    // d_in[3] = input_shape (int32), geometry compile-time fixed
    const float* wk   = (const float*)d_in[4];
    const float* bias = (const float*)d_in[5];

    fused_deeppoly_kernel<<<NB_BOUNDS + NB_WEIGHTS, 256, 0, stream>>>(
        x, lbp, ubp, wk, bias, (float*)d_out);

    // A/B probe: same store machinery, different destination buffer.
    // ws_size is constant per session -> same work every call.
    if (ws_size >= (size_t)NIN * NOUT * sizeof(float)) {
        weights_probe_kernel<<<NB_WEIGHTS, 256, 0, stream>>>(wk, (float*)d_ws);
    }
}

// Round 9
// 160.119 us; speedup vs baseline: 1.1358x; 1.1358x over previous
//
#include <hip/hip_runtime.h>

// Fixed geometry: input (1,16,16,16) -> NIN=4096; kernel (32,16,3,3), pad1 stride1 -> NOUT=8192
#define O_CH  32
#define C_CH  16
#define HH    16
#define WW    16
#define NPIX  256
#define NIN   4096
#define NOUT  8192
#define NB_BOUNDS  32     // blocks 0..31: bounds + concrete forward + bias_vec
#define NB_WEIGHTS 2048   // blocks 32..2079: weight matrix, global linear sweep

typedef float v4f __attribute__((ext_vector_type(4)));

// out layout (floats): x_out[8192] | lb[8192] | ub[8192] | weights[4096*8192] | bias_vec[8192]
//
// weights[n=(c,h,w)][col=(o,ph,pw)] = K[o,c,h-ph+1,w-pw+1] when offsets in [0,3), else 0.
//
// ROOFLINE NOTE (R8 A/B probe): this exact store machinery sustains 6.07 TB/s
// when pointed at d_ws (measured: +22.1 us for an extra 134 MB sweep), but
// ~2.3-2.7 TB/s into d_out; three store patterns and two occupancy levels into
// d_out are within noise of each other. The limit is a d_out buffer property
// (write path), not kernel structure. 134 MB must be written to d_out exactly
// once; we do one coalesced full-line float4 store per byte with KB-scale
// fetch. This kernel is at the d_out write roofline.
__global__ __launch_bounds__(256) void fused_deeppoly_kernel(
    const float* __restrict__ x,
    const float* __restrict__ lb,
    const float* __restrict__ ub,
    const float* __restrict__ wk,
    const float* __restrict__ bias,
    float* __restrict__ out) {
    const int b   = blockIdx.x;
    const int tid = threadIdx.x;

    if (b >= NB_BOUNDS) {
        // ---------------- unrolled weight matrix [NIN rows][NOUT cols] ----------------
        // Global linear sweep (fillBuffer-shaped): thread (b,t) stores float4
        // index c*524288 + (b-32)*256 + t; the grid advances 8 MiB per step, so
        // concurrent writes cover a contiguous multi-MB window (all channels).
        // Per-thread, column (o,ph,pw0) and row-parts h,w are loop-invariant;
        // c == iteration, so the inner loop is 3 L1 loads, 4 invariant-condition
        // selects, 1 plain float4 store, ptr += 8 MiB.
        const int bw  = b - NB_BOUNDS;
        const int nb  = bw >> 3;              // row base: n = c*256 + nb
        const int r   = (bw & 7) * 256 + tid; // float4 column index (0..2047)
        const int o   = r >> 6;
        const int p   = r & 63;
        const int ph  = p >> 2;
        const int pw0 = (p & 3) << 2;
        const int h   = nb >> 4;
        const int w   = nb & 15;
        const int kh  = h - ph + 1;
        const bool kvalid = (unsigned)kh < 3u;
        const int  khc = kvalid ? kh : 0;     // clamped for safe addressing
        const int  kw0 = w - pw0 + 1;         // kw of component m is kw0-m

        const bool vx0 = kvalid && kw0 == 0, vx1 = kvalid && kw0 == 1, vx2 = kvalid && kw0 == 2;
        const bool vy0 = kvalid && kw0 == 1, vy1 = kvalid && kw0 == 2, vy2 = kvalid && kw0 == 3;
        const bool vz0 = kvalid && kw0 == 2, vz1 = kvalid && kw0 == 3, vz2 = kvalid && kw0 == 4;
        const bool vw0 = kvalid && kw0 == 3, vw1 = kvalid && kw0 == 4, vw2 = kvalid && kw0 == 5;

        const float* kb = wk + (o * C_CH * 3 + khc) * 3;  // c = 0 slice
        v4f* p4 = (v4f*)(out + 3 * NOUT) + (size_t)bw * 256 + tid;

        #pragma unroll
        for (int c = 0; c < C_CH; ++c) {      // c == sweep iteration
            const float k0 = kb[0], k1 = kb[1], k2 = kb[2];
            v4f v;
            v.x = vx0 ? k0 : (vx1 ? k1 : (vx2 ? k2 : 0.f));
            v.y = vy0 ? k0 : (vy1 ? k1 : (vy2 ? k2 : 0.f));
            v.z = vz0 ? k0 : (vz1 ? k1 : (vz2 ? k2 : 0.f));
            v.w = vw0 ? k0 : (vw1 ? k1 : (vw2 ? k2 : 0.f));
            *p4 = v;                          // plain store, 1 KiB/wave contiguous
            p4 += 524288;                     // +8 MiB: next grid sweep step
            kb += 9;                          // next input channel
        }
    } else {
        // ---------------- bounds + concrete forward + bias_vec ----------------
        // Block owns output channel o (256 spatial outputs, one per thread).
        // Inputs (3 x 16 KB) + kernel slice are L1/L2-resident; these 32 blocks'
        // latency hides entirely under the 2048-block store flood.
        const int o  = b;
        const int ph = tid >> 4, pw = tid & 15;
        const float* kb_base = wk + o * C_CH * 9;
        float xa = 0.f, la = 0.f, ua = 0.f;
        #pragma unroll
        for (int c = 0; c < C_CH; ++c) {
            #pragma unroll
            for (int kh = 0; kh < 3; ++kh) {
                int h = ph + kh - 1;
                if ((unsigned)h >= (unsigned)HH) continue;
                #pragma unroll
                for (int kw = 0; kw < 3; ++kw) {
                    int w = pw + kw - 1;
                    if ((unsigned)w >= (unsigned)WW) continue;
                    float k   = kb_base[c * 9 + kh * 3 + kw];
                    int   idx = c * NPIX + h * WW + w;
                    xa = fmaf(k, x[idx], xa);
                    float lv = lb[idx], uv = ub[idx];
                    la = fmaf(k, (k < 0.f) ? uv : lv, la);
                    ua = fmaf(k, (k < 0.f) ? lv : uv, ua);
                }
            }
        }
        const int   t  = o * 256 + tid;
        const float bv = bias[o];
        out[t]            = xa + bv;         // x_out   (bias once)
        out[NOUT + t]     = la + 3.f * bv;   // lb_new  (bias 3x, per reference)
        out[2 * NOUT + t] = ua + 3.f * bv;   // ub_new
        out[(size_t)3 * NOUT + (size_t)NIN * NOUT + t] = bv;  // bias_vec
    }
}

extern "C" void kernel_launch(void* const* d_in, const int* in_sizes, int n_in,
                              void* d_out, int out_size, void* d_ws, size_t ws_size,
                              hipStream_t stream) {
    const float* x    = (const float*)d_in[0];
    const float* lbp  = (const float*)d_in[1];
    const float* ubp  = (const float*)d_in[2];
    // d_in[3] = input_shape (int32), geometry compile-time fixed
    const float* wk   = (const float*)d_in[4];
    const float* bias = (const float*)d_in[5];

    fused_deeppoly_kernel<<<NB_BOUNDS + NB_WEIGHTS, 256, 0, stream>>>(
        x, lbp, ubp, wk, bias, (float*)d_out);
}